// Round 3
// baseline (126.873 us; speedup 1.0000x reference)
//
#include <hip/hip_runtime.h>

typedef __attribute__((ext_vector_type(4))) float f32x4;
typedef __bf16 bf16x8 __attribute__((ext_vector_type(8)));
typedef unsigned short ushort_t;

#define T_TOK 8192   // B*S
#define DIM   1024   // D
#define NRCOL 2048   // N_FEAT * R

#define LGKM0() asm volatile("s_waitcnt lgkmcnt(0)" ::: "memory")
#define VMW(n)  asm volatile("s_waitcnt vmcnt(" #n ")" ::: "memory")
#define SB0()   __builtin_amdgcn_sched_barrier(0)
#define BAR()   __builtin_amdgcn_s_barrier()

static __device__ __forceinline__ unsigned short f2bf(float f) {
  unsigned int u = __builtin_bit_cast(unsigned int, f);
  u += 0x7fffu + ((u >> 16) & 1u);          // RNE
  return (unsigned short)(u >> 16);
}
static __device__ __forceinline__ float bfbits2f(unsigned int lo16) {
  return __builtin_bit_cast(float, lo16 << 16);
}
static __device__ __forceinline__ void gload16(const void* g, void* l) {
  __builtin_amdgcn_global_load_lds((const __attribute__((address_space(1))) void*)g,
                                   (__attribute__((address_space(3))) void*)l, 16, 0, 0);
}

// ---------------- f32 -> bf16 straight cast (x) ----------------
__global__ __launch_bounds__(256) void cvt_f32_bf16(const float* __restrict__ in,
                                                    unsigned short* __restrict__ out,
                                                    int n4) {
  int i = blockIdx.x * 256 + threadIdx.x;
  const int stride = gridDim.x * 256;
  const float4* in4 = (const float4*)in;
  uint2* o4 = (uint2*)out;
  for (; i < n4; i += stride) {
    float4 v = in4[i];
    uint2 o;
    o.x = (unsigned)f2bf(v.x) | ((unsigned)f2bf(v.y) << 16);
    o.y = (unsigned)f2bf(v.z) | ((unsigned)f2bf(v.w) << 16);
    o4[i] = o;
  }
}

// ---------------- tiled transpose + cast ----------------
__global__ __launch_bounds__(256) void tcvt(const float* __restrict__ src,
                                            unsigned short* __restrict__ dst,
                                            int rows, int cols,
                                            long sstride, long dstride) {
  src += (size_t)blockIdx.z * sstride;
  dst += (size_t)blockIdx.z * dstride;
  __shared__ float tile[32][33];
  const int tx = threadIdx.x & 31, ty = threadIdx.x >> 5;
  const int r0 = blockIdx.y * 32, c0 = blockIdx.x * 32;
  #pragma unroll
  for (int i = 0; i < 32; i += 8)
    tile[ty + i][tx] = src[(size_t)(r0 + ty + i) * cols + c0 + tx];
  __syncthreads();
  #pragma unroll
  for (int i = 0; i < 32; i += 8)
    dst[(size_t)(c0 + ty + i) * rows + r0 + tx] = f2bf(tile[tx][ty + i]);
}

// ---------------- bf16 GEMM: C[M,N] = A[M,K] * Bt[N,K]^T ----------------
// 256x128 tile, BK=64, 512 threads = 8 waves (4M x 2N, wave owns 64x64).
// Triple-buffered LDS (slot t%3; stage t+2 during t), phase-split schedule:
// 2 phases/tile x 16 MFMA, ds_read + stage interleaved per phase, counted
// vmcnt(6) once per tile (never 0 in steady state), setprio around MFMA,
// XOR chunk swizzle (both-sides), bijective XCD block swizzle.
template<bool OUT_BF16>
__global__ __launch_bounds__(512) void gemm3(const ushort_t* __restrict__ A,
                                             const ushort_t* __restrict__ Bt,
                                             void* __restrict__ Cp,
                                             int N, int K) {
  __shared__ ushort_t As[3][256 * 64];
  __shared__ ushort_t Bs[3][128 * 64];
  const int tid = threadIdx.x;
  const int nx = gridDim.x;
  const int orig = blockIdx.y * nx + blockIdx.x;
  const int q = (nx * gridDim.y) >> 3;          // grids are multiples of 8
  const int swz = (orig & 7) * q + (orig >> 3);
  const int bx = swz % nx, by = swz / nx;

  const int lane = tid & 63, wv = tid >> 6;
  const int wm = wv >> 1, wn = wv & 1;          // 4M x 2N
  const int lrow = lane & 15, lk = lane >> 4;

  const ushort_t* Ab = A + (size_t)by * 256 * K;
  const ushort_t* Bb = Bt + (size_t)bx * 128 * K;

  auto stageA = [&](int s, int kt, int r) {
    const int off = r * 8192 + tid * 16;        // byte offset in 32KB A tile
    const int row = off >> 7;                   // 128B rows (BK=64 bf16)
    const int ch = ((off >> 4) & 7) ^ (row & 7);
    gload16(Ab + (size_t)row * K + kt * 64 + ch * 8, (void*)&As[s][off >> 1]);
  };
  auto stageB = [&](int s, int kt, int r) {
    const int off = r * 8192 + tid * 16;        // byte offset in 16KB B tile
    const int row = off >> 7;
    const int ch = ((off >> 4) & 7) ^ (row & 7);
    gload16(Bb + (size_t)row * K + kt * 64 + ch * 8, (void*)&Bs[s][off >> 1]);
  };

  f32x4 acc[4][4];
  #pragma unroll
  for (int m = 0; m < 4; ++m)
    #pragma unroll
    for (int n = 0; n < 4; ++n)
      acc[m][n] = (f32x4){0.f, 0.f, 0.f, 0.f};

  const int nt = K >> 6;
  // prologue: tiles 0,1 -> slots 0,1; wait tile0 (6 oldest), tile1 in flight
  #pragma unroll
  for (int r = 0; r < 4; ++r) stageA(0, 0, r);
  #pragma unroll
  for (int r = 0; r < 2; ++r) stageB(0, 0, r);
  #pragma unroll
  for (int r = 0; r < 4; ++r) stageA(1, 1, r);
  #pragma unroll
  for (int r = 0; r < 2; ++r) stageB(1, 1, r);
  VMW(6); SB0(); BAR(); SB0();

  for (int t = 0; t < nt; ++t) {
    const int s = t % 3;
    const int s2 = (t + 2) % 3;
    const bool pf = (t + 2) < nt;
    bf16x8 av[4][2], bv[4][2];
    // ---- phase 1: read av[0..1], bv[0..3]; stage 3; MFMA m0-1 ----
    #pragma unroll
    for (int m = 0; m < 2; ++m)
      #pragma unroll
      for (int ks = 0; ks < 2; ++ks) {
        const int r = wm * 64 + m * 16 + lrow;
        const int ch = (ks * 4 + lk) ^ (r & 7);
        av[m][ks] = *(const bf16x8*)&As[s][r * 64 + ch * 8];
      }
    #pragma unroll
    for (int n = 0; n < 4; ++n)
      #pragma unroll
      for (int ks = 0; ks < 2; ++ks) {
        const int r = wn * 64 + n * 16 + lrow;
        const int ch = (ks * 4 + lk) ^ (r & 7);
        bv[n][ks] = *(const bf16x8*)&Bs[s][r * 64 + ch * 8];
      }
    if (pf) { stageA(s2, t + 2, 0); stageA(s2, t + 2, 1); stageB(s2, t + 2, 0); }
    SB0(); BAR(); LGKM0(); SB0();
    __builtin_amdgcn_s_setprio(1);
    #pragma unroll
    for (int ks = 0; ks < 2; ++ks)
      #pragma unroll
      for (int m = 0; m < 2; ++m)
        #pragma unroll
        for (int n = 0; n < 4; ++n)
          acc[m][n] = __builtin_amdgcn_mfma_f32_16x16x32_bf16(av[m][ks], bv[n][ks], acc[m][n], 0, 0, 0);
    __builtin_amdgcn_s_setprio(0);
    SB0(); BAR(); SB0();
    // ---- phase 2: read av[2..3]; stage 3; MFMA m2-3 ----
    #pragma unroll
    for (int m = 2; m < 4; ++m)
      #pragma unroll
      for (int ks = 0; ks < 2; ++ks) {
        const int r = wm * 64 + m * 16 + lrow;
        const int ch = (ks * 4 + lk) ^ (r & 7);
        av[m][ks] = *(const bf16x8*)&As[s][r * 64 + ch * 8];
      }
    if (pf) { stageA(s2, t + 2, 2); stageA(s2, t + 2, 3); stageB(s2, t + 2, 1); }
    SB0(); BAR(); LGKM0(); SB0();
    __builtin_amdgcn_s_setprio(1);
    #pragma unroll
    for (int ks = 0; ks < 2; ++ks)
      #pragma unroll
      for (int m = 2; m < 4; ++m)
        #pragma unroll
        for (int n = 0; n < 4; ++n)
          acc[m][n] = __builtin_amdgcn_mfma_f32_16x16x32_bf16(av[m][ks], bv[n][ks], acc[m][n], 0, 0, 0);
    __builtin_amdgcn_s_setprio(0);
    SB0();
    // counted wait: retire tile t+1's 6 loads; tile t+2's 6 stay in flight
    if (pf) { VMW(6); }
    else if (t + 1 < nt) { VMW(0); }
    SB0(); BAR(); SB0();
  }

  // epilogue: C/D layout col=lane&15, row=(lane>>4)*4+j
  #pragma unroll
  for (int m = 0; m < 4; ++m) {
    const int row0 = by * 256 + wm * 64 + m * 16 + lk * 4;
    #pragma unroll
    for (int n = 0; n < 4; ++n) {
      const int col = bx * 128 + wn * 64 + n * 16 + lrow;
      #pragma unroll
      for (int j = 0; j < 4; ++j) {
        const size_t idx = (size_t)(row0 + j) * N + col;
        if constexpr (OUT_BF16) ((ushort_t*)Cp)[idx] = f2bf(acc[m][n][j]);
        else                    ((float*)Cp)[idx] = acc[m][n][j];
      }
    }
  }
}

// ---------------- middle: h_all, router softmax, M = sum_p w (x) h ----------------
__global__ __launch_bounds__(256) void middle_kernel(const unsigned short* __restrict__ AH,
                                                     const float* __restrict__ fp,
                                                     const float* __restrict__ femb,
                                                     const float* __restrict__ Wr,
                                                     unsigned short* __restrict__ Mout,
                                                     float* __restrict__ auxout) {
  __shared__ float G[16][16];       // G[n][j] = sum_ds femb[n][ds]*Wr[ds][j]
  __shared__ float hs[4][2][128];
  __shared__ float wsm[4][2][16];
  const int tid = threadIdx.x;
  {
    const int n = tid >> 4, j = tid & 15;
    float s = 0.f;
    #pragma unroll
    for (int ds = 0; ds < 64; ++ds) s += femb[n * 64 + ds] * Wr[ds * 16 + j];
    G[n][j] = s;
  }
  const int wv = tid >> 6, l = tid & 63;
  const int t = blockIdx.x * 4 + wv;

  float p0[16], p1[16];
  #pragma unroll
  for (int n = 0; n < 16; ++n) {
    p0[n] = fp[t * 16 + n];
    p1[n] = fp[T_TOK * 16 + t * 16 + n];
  }

  float h00 = 0.f, h01 = 0.f, h10 = 0.f, h11 = 0.f;
  const unsigned short* ahrow = AH + (size_t)t * NRCOL;
  #pragma unroll
  for (int n = 0; n < 16; ++n) {
    const unsigned int v = *(const unsigned int*)(ahrow + n * 128 + 2 * l);
    const float a0 = bfbits2f(v & 0xffffu);
    const float a1 = bfbits2f(v >> 16);
    h00 += a0 * p0[n]; h01 += a1 * p0[n];
    h10 += a0 * p1[n]; h11 += a1 * p1[n];
  }
  hs[wv][0][2 * l] = h00; hs[wv][0][2 * l + 1] = h01;
  hs[wv][1][2 * l] = h10; hs[wv][1][2 * l + 1] = h11;
  __syncthreads();

  if (l < 32) {
    const int p = l >> 4, j = l & 15;
    float s = 0.f;
    #pragma unroll
    for (int n = 0; n < 16; ++n) s += (p ? p1[n] : p0[n]) * G[n][j];
    for (int r = 0; r < 128; ++r) s += hs[wv][p][r] * Wr[(64 + r) * 16 + j];
    float mx = s;
    #pragma unroll
    for (int d = 1; d < 16; d <<= 1) mx = fmaxf(mx, __shfl_xor(mx, d, 64));
    const float e = __expf(s - mx);
    float sum = e;
    #pragma unroll
    for (int d = 1; d < 16; d <<= 1) sum += __shfl_xor(sum, d, 64);
    wsm[wv][p][j] = e / sum;
  }
  __syncthreads();

  unsigned short* mrow = Mout + (size_t)t * NRCOL;
  #pragma unroll
  for (int n = 0; n < 16; ++n) {
    const float w0 = wsm[wv][0][n], w1 = wsm[wv][1][n];
    const float m0 = w0 * h00 + w1 * h10;   // r = 2l
    const float m1 = w0 * h01 + w1 * h11;   // r = 2l+1
    const unsigned int pk = (unsigned)f2bf(m0) | ((unsigned)f2bf(m1) << 16);
    *(unsigned int*)(mrow + n * 128 + 2 * l) = pk;
  }
  if (blockIdx.x == 0 && tid == 0) auxout[0] = 0.f;
}

extern "C" void kernel_launch(void* const* d_in, const int* in_sizes, int n_in,
                              void* d_out, int out_size, void* d_ws, size_t ws_size,
                              hipStream_t stream) {
  const float* x    = (const float*)d_in[0];
  const float* fp   = (const float*)d_in[1];
  const float* fk   = (const float*)d_in[2];
  const float* rk   = (const float*)d_in[3];
  const float* femb = (const float*)d_in[4];
  const float* Wr   = (const float*)d_in[5];
  float* out = (float*)d_out;

  char* ws = (char*)d_ws;
  unsigned short* Xbf = (unsigned short*)ws;
  unsigned short* W1t = (unsigned short*)(ws + 16u * 1024 * 1024);
  unsigned short* Mb  = (unsigned short*)ws;
  unsigned short* W2t = (unsigned short*)(ws + 32u * 1024 * 1024);
  unsigned short* AH  = (unsigned short*)(ws + 36u * 1024 * 1024);

  cvt_f32_bf16<<<2048, 256, 0, stream>>>(x, Xbf, (T_TOK * DIM) / 4);
  tcvt<<<dim3(128 / 32, 1024 / 32, 16), 256, 0, stream>>>(fk, W1t, 1024, 128,
                                                          1024L * 128, 128L * 1024);
  tcvt<<<dim3(1024 / 32, 2048 / 32, 1), 256, 0, stream>>>(rk, W2t, 2048, 1024, 0, 0);
  // all_h = Xbf @ W1t^T  -> AH bf16 [8192][2048]
  gemm3<true><<<dim3(NRCOL / 128, T_TOK / 256), 512, 0, stream>>>(Xbf, W1t, AH,
                                                                  NRCOL, DIM);
  middle_kernel<<<T_TOK / 4, 256, 0, stream>>>(AH, fp, femb, Wr, Mb, out + 8388608);
  // output = Mb @ W2t^T -> f32 d_out [8192][1024]
  gemm3<false><<<dim3(DIM / 128, T_TOK / 256), 512, 0, stream>>>(Mb, W2t, out,
                                                                 DIM, NRCOL);
}

// Round 4
// 117.910 us; speedup vs baseline: 1.0760x; 1.0760x over previous
//
#include <hip/hip_runtime.h>

typedef __attribute__((ext_vector_type(4))) float f32x4;
typedef __bf16 bf16x8 __attribute__((ext_vector_type(8)));
typedef unsigned short ushort_t;

#define T_TOK 8192   // B*S
#define DIM   1024   // D
#define NRCOL 2048   // N_FEAT * R

#define LGKM0() asm volatile("s_waitcnt lgkmcnt(0)" ::: "memory")
#define VMW(n)  asm volatile("s_waitcnt vmcnt(" #n ")" ::: "memory")
#define SB0()   __builtin_amdgcn_sched_barrier(0)
#define BAR()   __builtin_amdgcn_s_barrier()

static __device__ __forceinline__ unsigned short f2bf(float f) {
  unsigned int u = __builtin_bit_cast(unsigned int, f);
  u += 0x7fffu + ((u >> 16) & 1u);          // RNE
  return (unsigned short)(u >> 16);
}
static __device__ __forceinline__ float bfbits2f(unsigned int lo16) {
  return __builtin_bit_cast(float, lo16 << 16);
}
static __device__ __forceinline__ void gload16(const void* g, void* l) {
  __builtin_amdgcn_global_load_lds((const __attribute__((address_space(1))) void*)g,
                                   (__attribute__((address_space(3))) void*)l, 16, 0, 0);
}

// ---------------- f32 -> bf16 straight cast (x) ----------------
__global__ __launch_bounds__(256) void cvt_f32_bf16(const float* __restrict__ in,
                                                    unsigned short* __restrict__ out,
                                                    int n4) {
  int i = blockIdx.x * 256 + threadIdx.x;
  const int stride = gridDim.x * 256;
  const float4* in4 = (const float4*)in;
  uint2* o4 = (uint2*)out;
  for (; i < n4; i += stride) {
    float4 v = in4[i];
    uint2 o;
    o.x = (unsigned)f2bf(v.x) | ((unsigned)f2bf(v.y) << 16);
    o.y = (unsigned)f2bf(v.z) | ((unsigned)f2bf(v.w) << 16);
    o4[i] = o;
  }
}

// ---------------- tiled transpose + cast ----------------
__global__ __launch_bounds__(256) void tcvt(const float* __restrict__ src,
                                            unsigned short* __restrict__ dst,
                                            int rows, int cols,
                                            long sstride, long dstride) {
  src += (size_t)blockIdx.z * sstride;
  dst += (size_t)blockIdx.z * dstride;
  __shared__ float tile[32][33];
  const int tx = threadIdx.x & 31, ty = threadIdx.x >> 5;
  const int r0 = blockIdx.y * 32, c0 = blockIdx.x * 32;
  #pragma unroll
  for (int i = 0; i < 32; i += 8)
    tile[ty + i][tx] = src[(size_t)(r0 + ty + i) * cols + c0 + tx];
  __syncthreads();
  #pragma unroll
  for (int i = 0; i < 32; i += 8)
    dst[(size_t)(c0 + ty + i) * rows + r0 + tx] = f2bf(tile[tx][ty + i]);
}

// =====================================================================
// gemm4: C[M,N] = A[M,K]*Bt[N,K]^T, 256x256 tile, BK=64, 512thr = 8 waves
// (2M x 4N, wave owns 128x64). m201-style 4-phase schedule: per phase
// {<=12 ds_read, 2 gload_lds stage, BAR, lgkm0, setprio, 16 MFMA, BAR};
// region-staggered double-buffer staging, vmcnt(6) once per K-tile.
// =====================================================================
template<bool OUT_BF16>
__global__ __launch_bounds__(512, 2) void gemm4(const ushort_t* __restrict__ A,
                                                const ushort_t* __restrict__ Bt,
                                                void* __restrict__ Cp,
                                                int N, int K) {
  __shared__ ushort_t As[2][256 * 64];
  __shared__ ushort_t Bs[2][256 * 64];
  const int tid = threadIdx.x;
  const int nx = gridDim.x;
  const int orig = blockIdx.y * nx + blockIdx.x;
  const int q = (nx * gridDim.y) >> 3;          // grids are multiples of 8
  const int swz = (orig & 7) * q + (orig >> 3);
  const int bx = swz % nx, by = swz / nx;

  const int lane = tid & 63, wv = tid >> 6;
  const int wm = wv >> 2, wn = wv & 3;          // 2M x 4N
  const int lrow = lane & 15, lk = lane >> 4;
  const int sub8 = lane >> 3, ch8 = lane & 7;   // staging decomposition

  const ushort_t* Ab = A + (size_t)by * 256 * K;
  const ushort_t* Bb = Bt + (size_t)bx * 256 * K;

  // stage one 64-row A round (rows R0..R0+63) into buffer s for k-tile kt
  auto stA = [&](int s, int kt, int R0) {
    const int row = R0 + wv * 8 + sub8;
    const int sc = ch8 ^ (row & 7);
    gload16(Ab + (size_t)row * K + kt * 64 + sc * 8, (void*)&As[s][row * 64 + ch8 * 8]);
  };
  // stage B strip-round: half in {0,1} (n01 / n23 rows), r in {0,1}
  auto stB = [&](int s, int kt, int half, int r) {
    const int c = r * 8 + wv;
    const int row = (c >> 2) * 64 + half * 32 + (c & 3) * 8 + sub8;
    const int sc = ch8 ^ (row & 7);
    gload16(Bb + (size_t)row * K + kt * 64 + sc * 8, (void*)&Bs[s][row * 64 + ch8 * 8]);
  };
  auto rdA = [&](int s, int m, int ks) {
    const int r = wm * 128 + m * 16 + lrow;
    const int ch = (ks * 4 + lk) ^ (r & 7);
    return *(const bf16x8*)&As[s][r * 64 + ch * 8];
  };
  auto rdB = [&](int s, int n, int ks) {
    const int r = wn * 64 + n * 16 + lrow;
    const int ch = (ks * 4 + lk) ^ (r & 7);
    return *(const bf16x8*)&Bs[s][r * 64 + ch * 8];
  };

  f32x4 acc[8][4];
  #pragma unroll
  for (int m = 0; m < 8; ++m)
    #pragma unroll
    for (int n = 0; n < 4; ++n)
      acc[m][n] = (f32x4){0.f, 0.f, 0.f, 0.f};

  const int nt = K >> 6;
  // prologue: tile0 full (8 rounds) + tile1 {Am03,Bn01,Bn23} (6 rounds)
  stA(0, 0, 0); stA(0, 0, 128); stA(0, 0, 64); stA(0, 0, 192);
  stB(0, 0, 0, 0); stB(0, 0, 0, 1); stB(0, 0, 1, 0); stB(0, 0, 1, 1);
  stA(1, 1, 0); stA(1, 1, 128);
  stB(1, 1, 0, 0); stB(1, 1, 0, 1); stB(1, 1, 1, 0); stB(1, 1, 1, 1);
  VMW(6); SB0(); BAR(); SB0();

  for (int t = 0; t < nt; ++t) {
    const int s = t & 1, so = s ^ 1;
    bf16x8 av1[4][2], av2[4][2], bv1[2][2], bv2[2][2];
    // ---- P1: read av(m0-3)+bv(n0-1); stage Am47(t+1); MFMA Q(m0-3,n0-1)
    #pragma unroll
    for (int m = 0; m < 4; ++m)
      #pragma unroll
      for (int ks = 0; ks < 2; ++ks) av1[m][ks] = rdA(s, m, ks);
    #pragma unroll
    for (int n = 0; n < 2; ++n)
      #pragma unroll
      for (int ks = 0; ks < 2; ++ks) bv1[n][ks] = rdB(s, n, ks);
    if (t + 1 < nt) { stA(so, t + 1, 64); stA(so, t + 1, 192); }
    SB0(); BAR(); LGKM0(); SB0();
    __builtin_amdgcn_s_setprio(1);
    #pragma unroll
    for (int ks = 0; ks < 2; ++ks)
      #pragma unroll
      for (int m = 0; m < 4; ++m)
        #pragma unroll
        for (int n = 0; n < 2; ++n)
          acc[m][n] = __builtin_amdgcn_mfma_f32_16x16x32_bf16(av1[m][ks], bv1[n][ks], acc[m][n], 0, 0, 0);
    __builtin_amdgcn_s_setprio(0);
    SB0(); BAR(); SB0();
    // ---- P2: read bv(n2-3); stage Am03(t+2); MFMA Q(m0-3,n2-3)
    #pragma unroll
    for (int n = 0; n < 2; ++n)
      #pragma unroll
      for (int ks = 0; ks < 2; ++ks) bv2[n][ks] = rdB(s, n + 2, ks);
    if (t + 2 < nt) { stA(s, t + 2, 0); stA(s, t + 2, 128); }
    SB0(); BAR(); LGKM0(); SB0();
    __builtin_amdgcn_s_setprio(1);
    #pragma unroll
    for (int ks = 0; ks < 2; ++ks)
      #pragma unroll
      for (int m = 0; m < 4; ++m)
        #pragma unroll
        for (int n = 0; n < 2; ++n)
          acc[m][n + 2] = __builtin_amdgcn_mfma_f32_16x16x32_bf16(av1[m][ks], bv2[n][ks], acc[m][n + 2], 0, 0, 0);
    __builtin_amdgcn_s_setprio(0);
    SB0(); BAR(); SB0();
    // ---- P3: read av(m4-7); stage Bn01(t+2); MFMA Q(m4-7,n0-1)
    #pragma unroll
    for (int m = 0; m < 4; ++m)
      #pragma unroll
      for (int ks = 0; ks < 2; ++ks) av2[m][ks] = rdA(s, m + 4, ks);
    if (t + 2 < nt) { stB(s, t + 2, 0, 0); stB(s, t + 2, 0, 1); }
    SB0(); BAR(); LGKM0(); SB0();
    __builtin_amdgcn_s_setprio(1);
    #pragma unroll
    for (int ks = 0; ks < 2; ++ks)
      #pragma unroll
      for (int m = 0; m < 4; ++m)
        #pragma unroll
        for (int n = 0; n < 2; ++n)
          acc[m + 4][n] = __builtin_amdgcn_mfma_f32_16x16x32_bf16(av2[m][ks], bv1[n][ks], acc[m + 4][n], 0, 0, 0);
    __builtin_amdgcn_s_setprio(0);
    SB0(); BAR(); SB0();
    // ---- P4: stage Bn23(t+2); MFMA Q(m4-7,n2-3); vmcnt(6); barrier
    if (t + 2 < nt) { stB(s, t + 2, 1, 0); stB(s, t + 2, 1, 1); }
    SB0();
    __builtin_amdgcn_s_setprio(1);
    #pragma unroll
    for (int ks = 0; ks < 2; ++ks)
      #pragma unroll
      for (int m = 0; m < 4; ++m)
        #pragma unroll
        for (int n = 0; n < 2; ++n)
          acc[m + 4][n + 2] = __builtin_amdgcn_mfma_f32_16x16x32_bf16(av2[m][ks], bv2[n][ks], acc[m + 4][n + 2], 0, 0, 0);
    __builtin_amdgcn_s_setprio(0);
    SB0();
    if (t + 2 < nt) { VMW(6); } else { VMW(0); }
    SB0(); BAR(); SB0();
  }

  #pragma unroll
  for (int m = 0; m < 8; ++m) {
    const int row0 = by * 256 + wm * 128 + m * 16 + lk * 4;
    #pragma unroll
    for (int n = 0; n < 4; ++n) {
      const int col = bx * 256 + wn * 64 + n * 16 + lrow;
      #pragma unroll
      for (int j = 0; j < 4; ++j) {
        const size_t idx = (size_t)(row0 + j) * N + col;
        if constexpr (OUT_BF16) ((ushort_t*)Cp)[idx] = f2bf(acc[m][n][j]);
        else                    ((float*)Cp)[idx] = acc[m][n][j];
      }
    }
  }
}

// =====================================================================
// gemm2p: 128x256 tile, BK=64, 512thr = 8 waves (2M x 4N, wave 64x64).
// 2-phase variant of the same staggered ledger, vmcnt(3) per K-tile.
// =====================================================================
__global__ __launch_bounds__(512, 2) void gemm2p(const ushort_t* __restrict__ A,
                                                 const ushort_t* __restrict__ Bt,
                                                 float* __restrict__ Cp,
                                                 int N, int K) {
  __shared__ ushort_t As[2][128 * 64];
  __shared__ ushort_t Bs[2][256 * 64];
  const int tid = threadIdx.x;
  const int nx = gridDim.x;
  const int orig = blockIdx.y * nx + blockIdx.x;
  const int q = (nx * gridDim.y) >> 3;
  const int swz = (orig & 7) * q + (orig >> 3);
  const int bx = swz % nx, by = swz / nx;

  const int lane = tid & 63, wv = tid >> 6;
  const int wm = wv >> 2, wn = wv & 3;
  const int lrow = lane & 15, lk = lane >> 4;
  const int sub8 = lane >> 3, ch8 = lane & 7;

  const ushort_t* Ab = A + (size_t)by * 128 * K;
  const ushort_t* Bb = Bt + (size_t)bx * 256 * K;

  auto stA = [&](int s, int kt, int R0) {
    const int row = R0 + wv * 8 + sub8;
    const int sc = ch8 ^ (row & 7);
    gload16(Ab + (size_t)row * K + kt * 64 + sc * 8, (void*)&As[s][row * 64 + ch8 * 8]);
  };
  auto stB = [&](int s, int kt, int half, int r) {
    const int c = r * 8 + wv;
    const int row = (c >> 2) * 64 + half * 32 + (c & 3) * 8 + sub8;
    const int sc = ch8 ^ (row & 7);
    gload16(Bb + (size_t)row * K + kt * 64 + sc * 8, (void*)&Bs[s][row * 64 + ch8 * 8]);
  };
  auto rdA = [&](int s, int m, int ks) {
    const int r = wm * 64 + m * 16 + lrow;
    const int ch = (ks * 4 + lk) ^ (r & 7);
    return *(const bf16x8*)&As[s][r * 64 + ch * 8];
  };
  auto rdB = [&](int s, int n, int ks) {
    const int r = wn * 64 + n * 16 + lrow;
    const int ch = (ks * 4 + lk) ^ (r & 7);
    return *(const bf16x8*)&Bs[s][r * 64 + ch * 8];
  };

  f32x4 acc[4][4];
  #pragma unroll
  for (int m = 0; m < 4; ++m)
    #pragma unroll
    for (int n = 0; n < 4; ++n)
      acc[m][n] = (f32x4){0.f, 0.f, 0.f, 0.f};

  const int nt = K >> 6;
  // prologue: tile0 full (6 rounds) + tile1 {A, Bn01 r0} (3 rounds)
  stA(0, 0, 0); stA(0, 0, 64);
  stB(0, 0, 0, 0); stB(0, 0, 0, 1); stB(0, 0, 1, 0); stB(0, 0, 1, 1);
  stA(1, 1, 0); stA(1, 1, 64); stB(1, 1, 0, 0);
  VMW(3); SB0(); BAR(); SB0();

  for (int t = 0; t < nt; ++t) {
    const int s = t & 1, so = s ^ 1;
    bf16x8 av[4][2], bv1[2][2], bv2[2][2];
    // ---- P1: read av(all)+bv(n0-1); stage Bn23(t+1)+Bn01(t+1)r1; MFMA n0-1
    #pragma unroll
    for (int m = 0; m < 4; ++m)
      #pragma unroll
      for (int ks = 0; ks < 2; ++ks) av[m][ks] = rdA(s, m, ks);
    #pragma unroll
    for (int n = 0; n < 2; ++n)
      #pragma unroll
      for (int ks = 0; ks < 2; ++ks) bv1[n][ks] = rdB(s, n, ks);
    if (t + 1 < nt) { stB(so, t + 1, 1, 0); stB(so, t + 1, 1, 1); stB(so, t + 1, 0, 1); }
    SB0(); BAR(); LGKM0(); SB0();
    __builtin_amdgcn_s_setprio(1);
    #pragma unroll
    for (int ks = 0; ks < 2; ++ks)
      #pragma unroll
      for (int m = 0; m < 4; ++m)
        #pragma unroll
        for (int n = 0; n < 2; ++n)
          acc[m][n] = __builtin_amdgcn_mfma_f32_16x16x32_bf16(av[m][ks], bv1[n][ks], acc[m][n], 0, 0, 0);
    __builtin_amdgcn_s_setprio(0);
    SB0(); BAR(); SB0();
    // ---- P2: read bv(n2-3); stage A(t+2)+Bn01(t+2)r0; MFMA n2-3; vmcnt(3)
    #pragma unroll
    for (int n = 0; n < 2; ++n)
      #pragma unroll
      for (int ks = 0; ks < 2; ++ks) bv2[n][ks] = rdB(s, n + 2, ks);
    if (t + 2 < nt) { stA(s, t + 2, 0); stA(s, t + 2, 64); stB(s, t + 2, 0, 0); }
    SB0(); BAR(); LGKM0(); SB0();
    __builtin_amdgcn_s_setprio(1);
    #pragma unroll
    for (int ks = 0; ks < 2; ++ks)
      #pragma unroll
      for (int m = 0; m < 4; ++m)
        #pragma unroll
        for (int n = 0; n < 2; ++n)
          acc[m][n + 2] = __builtin_amdgcn_mfma_f32_16x16x32_bf16(av[m][ks], bv2[n][ks], acc[m][n + 2], 0, 0, 0);
    __builtin_amdgcn_s_setprio(0);
    SB0();
    if (t + 2 < nt) { VMW(3); } else { VMW(0); }
    SB0(); BAR(); SB0();
  }

  #pragma unroll
  for (int m = 0; m < 4; ++m) {
    const int row0 = by * 128 + wm * 64 + m * 16 + lk * 4;
    #pragma unroll
    for (int n = 0; n < 4; ++n) {
      const int col = bx * 256 + wn * 64 + n * 16 + lrow;
      #pragma unroll
      for (int j = 0; j < 4; ++j)
        Cp[(size_t)(row0 + j) * N + col] = acc[m][n][j];
    }
  }
}

// ---------------- middle: h_all, router softmax, M = sum_p w (x) h ----------------
__global__ __launch_bounds__(256) void middle_kernel(const unsigned short* __restrict__ AH,
                                                     const float* __restrict__ fp,
                                                     const float* __restrict__ femb,
                                                     const float* __restrict__ Wr,
                                                     unsigned short* __restrict__ Mout,
                                                     float* __restrict__ auxout) {
  __shared__ float G[16][16];
  __shared__ float hs[4][2][128];
  __shared__ float wsm[4][2][16];
  const int tid = threadIdx.x;
  {
    const int n = tid >> 4, j = tid & 15;
    float s = 0.f;
    #pragma unroll
    for (int ds = 0; ds < 64; ++ds) s += femb[n * 64 + ds] * Wr[ds * 16 + j];
    G[n][j] = s;
  }
  const int wv = tid >> 6, l = tid & 63;
  const int t = blockIdx.x * 4 + wv;

  float p0[16], p1[16];
  #pragma unroll
  for (int n = 0; n < 16; ++n) {
    p0[n] = fp[t * 16 + n];
    p1[n] = fp[T_TOK * 16 + t * 16 + n];
  }

  float h00 = 0.f, h01 = 0.f, h10 = 0.f, h11 = 0.f;
  const unsigned short* ahrow = AH + (size_t)t * NRCOL;
  #pragma unroll
  for (int n = 0; n < 16; ++n) {
    const unsigned int v = *(const unsigned int*)(ahrow + n * 128 + 2 * l);
    const float a0 = bfbits2f(v & 0xffffu);
    const float a1 = bfbits2f(v >> 16);
    h00 += a0 * p0[n]; h01 += a1 * p0[n];
    h10 += a0 * p1[n]; h11 += a1 * p1[n];
  }
  hs[wv][0][2 * l] = h00; hs[wv][0][2 * l + 1] = h01;
  hs[wv][1][2 * l] = h10; hs[wv][1][2 * l + 1] = h11;
  __syncthreads();

  if (l < 32) {
    const int p = l >> 4, j = l & 15;
    float s = 0.f;
    #pragma unroll
    for (int n = 0; n < 16; ++n) s += (p ? p1[n] : p0[n]) * G[n][j];
    for (int r = 0; r < 128; ++r) s += hs[wv][p][r] * Wr[(64 + r) * 16 + j];
    float mx = s;
    #pragma unroll
    for (int d = 1; d < 16; d <<= 1) mx = fmaxf(mx, __shfl_xor(mx, d, 64));
    const float e = __expf(s - mx);
    float sum = e;
    #pragma unroll
    for (int d = 1; d < 16; d <<= 1) sum += __shfl_xor(sum, d, 64);
    wsm[wv][p][j] = e / sum;
  }
  __syncthreads();

  unsigned short* mrow = Mout + (size_t)t * NRCOL;
  #pragma unroll
  for (int n = 0; n < 16; ++n) {
    const float w0 = wsm[wv][0][n], w1 = wsm[wv][1][n];
    const float m0 = w0 * h00 + w1 * h10;
    const float m1 = w0 * h01 + w1 * h11;
    const unsigned int pk = (unsigned)f2bf(m0) | ((unsigned)f2bf(m1) << 16);
    *(unsigned int*)(mrow + n * 128 + 2 * l) = pk;
  }
  if (blockIdx.x == 0 && tid == 0) auxout[0] = 0.f;
}

extern "C" void kernel_launch(void* const* d_in, const int* in_sizes, int n_in,
                              void* d_out, int out_size, void* d_ws, size_t ws_size,
                              hipStream_t stream) {
  const float* x    = (const float*)d_in[0];
  const float* fp   = (const float*)d_in[1];
  const float* fk   = (const float*)d_in[2];
  const float* rk   = (const float*)d_in[3];
  const float* femb = (const float*)d_in[4];
  const float* Wr   = (const float*)d_in[5];
  float* out = (float*)d_out;

  char* ws = (char*)d_ws;
  unsigned short* Xbf = (unsigned short*)ws;
  unsigned short* W1t = (unsigned short*)(ws + 16u * 1024 * 1024);
  unsigned short* Mb  = (unsigned short*)ws;
  unsigned short* W2t = (unsigned short*)(ws + 32u * 1024 * 1024);
  unsigned short* AH  = (unsigned short*)(ws + 36u * 1024 * 1024);

  cvt_f32_bf16<<<2048, 256, 0, stream>>>(x, Xbf, (T_TOK * DIM) / 4);
  tcvt<<<dim3(128 / 32, 1024 / 32, 16), 256, 0, stream>>>(fk, W1t, 1024, 128,
                                                          1024L * 128, 128L * 1024);
  tcvt<<<dim3(1024 / 32, 2048 / 32, 1), 256, 0, stream>>>(rk, W2t, 2048, 1024, 0, 0);
  // all_h = Xbf @ W1t^T -> AH bf16 [8192][2048]
  gemm4<true><<<dim3(NRCOL / 256, T_TOK / 256), 512, 0, stream>>>(Xbf, W1t, AH,
                                                                  NRCOL, DIM);
  middle_kernel<<<T_TOK / 4, 256, 0, stream>>>(AH, fp, femb, Wr, Mb, out + 8388608);
  // output = Mb @ W2t^T -> f32 d_out [8192][1024]
  gemm2p<<<dim3(DIM / 256, T_TOK / 128), 512, 0, stream>>>(Mb, W2t, out,
                                                           DIM, NRCOL);
}